// Round 18
// baseline (181.868 us; speedup 1.0000x reference)
//
#include <hip/hip_runtime.h>
#include <hip/hip_bf16.h>

typedef __attribute__((ext_vector_type(8))) short short8;
typedef __attribute__((ext_vector_type(4))) short short4v;
typedef __attribute__((ext_vector_type(4))) float f32x4;

__device__ __forceinline__ unsigned short f2bf(float f) {
    union { __hip_bfloat16 b; unsigned short u; } v;
    v.b = __float2bfloat16(f);
    return v.u;
}
__device__ __forceinline__ float bf2f(unsigned short u) {
    return __uint_as_float(((unsigned)u) << 16);
}
__device__ __forceinline__ float gelu_tanh(float x) {
    float u = 0.79788456080286536f * x * (1.0f + 0.044715f * x * x);
    return x * __builtin_amdgcn_rcpf(1.0f + __builtin_exp2f(-2.8853900817779268f * u));
}
__device__ __forceinline__ float sigmoidf(float x) {
    return __builtin_amdgcn_rcpf(1.0f + __builtin_exp2f(-1.4426950408889634f * x));
}
__device__ __forceinline__ int swz(int row, int col) {  // short-index swizzle
    return (row * 64 + col) ^ ((row & 7) << 3);
}

// ---------------- prepack: fp32 weights -> bf16 MFMA fragment layout in ws ----------------
// layout (shorts): W1[m] at m*36864 ; W2[m] at 110592+m*4096 ; GATE(320x64 eff.) at 122880
__global__ __launch_bounds__(256)
void prepack_kernel(const float* __restrict__ w1r, const float* __restrict__ w1c,
                    const float* __restrict__ w1b,
                    const float* __restrict__ w2r, const float* __restrict__ w2c,
                    const float* __restrict__ w2b,
                    const float* __restrict__ gw, unsigned short* __restrict__ ws)
{
    int t = blockIdx.x * 256 + threadIdx.x;
    if (t < 13824) {
        int wi = t / 4608, r = t % 4608;
        const float* src = (wi == 0) ? w1r : (wi == 1) ? w1c : w1b;
        unsigned short* dst = ws + wi * 36864;
        int lane = r & 63;
        int col = ((r >> 6) & 3) * 16 + (lane & 15);
        int k0 = (r >> 8) * 32 + (lane >> 4) * 8;
        #pragma unroll
        for (int j = 0; j < 8; ++j) dst[r * 8 + j] = f2bf(src[(k0 + j) * 64 + col]);
    } else if (t < 15360) {
        int q = t - 13824, wi = q / 512, r = q % 512;
        const float* src = (wi == 0) ? w2r : (wi == 1) ? w2c : w2b;
        unsigned short* dst = ws + 110592 + wi * 4096;
        int lane = r & 63;
        int col = ((r >> 6) & 3) * 16 + (lane & 15);
        int k0 = (r >> 8) * 32 + (lane >> 4) * 8;
        #pragma unroll
        for (int j = 0; j < 8; ++j) dst[r * 8 + j] = f2bf(src[(k0 + j) * 64 + col]);
    } else if (t < 17920) {
        int r = t - 15360;
        unsigned short* dst = ws + 122880;
        int lane = r & 63;
        int col = ((r >> 6) & 3) * 16 + (lane & 15);
        int k0 = (r >> 8) * 32 + (lane >> 4) * 8;
        #pragma unroll
        for (int j = 0; j < 8; ++j) {
            int krow = k0 + j;
            float v;
            if (krow < 128) {
                v = gw[krow * 64 + col];
            } else {
                int c = (krow - 128) >> 6, e = (krow - 128) & 63;
                int lo = 3 * e - 64 * c;
                v = 0.f;
                #pragma unroll
                for (int s = 0; s < 3; ++s) {
                    int dp = lo + s;
                    if (dp >= 0 && dp < 64) v += gw[(128 + dp) * 64 + col];
                }
            }
            dst[r * 8 + j] = f2bf(v);
        }
    }
}

// ================= Kernel 1: NB=4, 12 waves = (type x feature-quarter), weights amortized 3x =================
// ws UP layout (shorts, base UPWS_OFF): [(b*27 + slot)*64 + f], slot: 0-8 row, 9-17 col, 18-26 box
#define UPWS_OFF 147456

__global__ __launch_bounds__(768, 2)
void k1_mlp(const float* __restrict__ z,
            const float* __restrict__ b1r, const float* __restrict__ b2r,
            const float* __restrict__ b1c, const float* __restrict__ b2c,
            const float* __restrict__ b1b, const float* __restrict__ b2b,
            const short* __restrict__ wsp, unsigned short* __restrict__ upws)
{
    __shared__ __align__(16) unsigned short zl[20736];  // 4 b x 81 cells x 64 f (41.5 KB)
    __shared__ __align__(16) unsigned short hlds[9216]; // 9 tiles x 16x64 (18 KB)
    const int t = threadIdx.x;
    const int lane = t & 63;
    const int w = t >> 6;          // 0..11
    const int rl = lane & 15;
    const int kg = lane >> 4;
    const int b0 = blockIdx.x * 4;

    // ---- stage z: 4*5184 floats, coalesced stream, inline f32->bf16 ----
    {
        const float* src = z + (size_t)b0 * 5184;
        for (int g = t; g < 5184; g += 768) {
            float4 v = *(const float4*)(src + g * 4);
            int row = g >> 4;           // b*81 + cell
            int col = (g & 15) * 4;
            uint2 pk;
            pk.x = ((unsigned)f2bf(v.y) << 16) | f2bf(v.x);
            pk.y = ((unsigned)f2bf(v.w) << 16) | f2bf(v.z);
            *(uint2*)&zl[swz(row, col)] = pk;
        }
    }
    __syncthreads();

    // ---- K-loop: wave (T, nq) computes feature quarter nq of all 3 tiles of type T ----
    const int T = w >> 2, nq = w & 3;
    const short* w1p = wsp + T * 36864;
    const float* b1p = (T == 0) ? b1r : (T == 1) ? b1c : b1b;
    const float b1s = b1p[nq * 16 + rl];

    const int b = rl & 3, js = rl >> 2;
    int rb0, rb1, rb2;
    {
        int j0 = 0 * 4 + js;  j0 = (j0 < 9) ? j0 : 8;
        int j1 = 1 * 4 + js;  j1 = (j1 < 9) ? j1 : 8;
        int j2 = 2 * 4 + js;  j2 = (j2 < 9) ? j2 : 8;
        int c0 = (T == 0) ? j0 * 9 : (T == 1) ? j0 : (j0 / 3) * 27 + (j0 % 3) * 3;
        int c1 = (T == 0) ? j1 * 9 : (T == 1) ? j1 : (j1 / 3) * 27 + (j1 % 3) * 3;
        int c2 = (T == 0) ? j2 * 9 : (T == 1) ? j2 : (j2 / 3) * 27 + (j2 % 3) * 3;
        rb0 = b * 81 + c0; rb1 = b * 81 + c1; rb2 = b * 81 + c2;
    }

    f32x4 acc0 = (f32x4)0.f, acc1 = (f32x4)0.f, acc2 = (f32x4)0.f;

    #pragma unroll
    for (int kk = 0; kk < 18; ++kk) {
        const int s = kk >> 1;
        const int sadd = (T == 0) ? s : (T == 1) ? 9 * s : (s / 3) * 9 + (s % 3);
        const int feat = (kk & 1) * 32 + kg * 8;
        short8 bv = *(const short8*)(w1p + ((kk * 4 + nq) * 64 + lane) * 8);
        short8 a0 = *(const short8*)&zl[swz(rb0 + sadd, feat)];
        short8 a1 = *(const short8*)&zl[swz(rb1 + sadd, feat)];
        short8 a2 = *(const short8*)&zl[swz(rb2 + sadd, feat)];
        acc0 = __builtin_amdgcn_mfma_f32_16x16x32_bf16(a0, bv, acc0, 0, 0, 0);
        acc1 = __builtin_amdgcn_mfma_f32_16x16x32_bf16(a1, bv, acc1, 0, 0, 0);
        acc2 = __builtin_amdgcn_mfma_f32_16x16x32_bf16(a2, bv, acc2, 0, 0, 0);
    }

    // ---- gelu+bias -> H (cross-wave assembly: 4 nq-waves fill each tile) ----
    #pragma unroll
    for (int reg = 0; reg < 4; ++reg) {
        hlds[(T * 3 + 0) * 1024 + swz(kg * 4 + reg, nq * 16 + rl)] = f2bf(gelu_tanh(acc0[reg] + b1s));
        hlds[(T * 3 + 1) * 1024 + swz(kg * 4 + reg, nq * 16 + rl)] = f2bf(gelu_tanh(acc1[reg] + b1s));
        hlds[(T * 3 + 2) * 1024 + swz(kg * 4 + reg, nq * 16 + rl)] = f2bf(gelu_tanh(acc2[reg] + b1s));
    }
    __syncthreads();

    // ---- stage 2 + UP store: waves 0..8, tile w (type T2, group pg2) ----
    // NOTE: no lgkmcnt(0) drains here — hlds[hoff] is wave-private after the barrier;
    // same-wave DS ops execute in order (WAR/RAW safe), compiler inserts counted waits.
    if (w < 9) {
        const int T2 = w / 3, pg2 = w % 3;
        const int hoff = w * 1024;
        const short* w2p = wsp + 110592 + T2 * 4096;
        const float* b2p = (T2 == 0) ? b2r : (T2 == 1) ? b2c : b2b;
        float b2v[4];
        #pragma unroll
        for (int nt = 0; nt < 4; ++nt) b2v[nt] = b2p[nt * 16 + rl];

        f32x4 a2c[4];
        #pragma unroll
        for (int nt = 0; nt < 4; ++nt) a2c[nt] = (f32x4)0.f;
        #pragma unroll
        for (int kk2 = 0; kk2 < 2; ++kk2) {
            short8 a2 = *(const short8*)&hlds[hoff + swz(rl, kk2 * 32 + kg * 8)];
            #pragma unroll
            for (int nt = 0; nt < 4; ++nt) {
                short8 bw = *(const short8*)(w2p + ((kk2 * 4 + nt) * 64 + lane) * 8);
                a2c[nt] = __builtin_amdgcn_mfma_f32_16x16x32_bf16(a2, bw, a2c[nt], 0, 0, 0);
            }
        }
        #pragma unroll
        for (int nt = 0; nt < 4; ++nt)
            #pragma unroll
            for (int reg = 0; reg < 4; ++reg)
                hlds[hoff + swz(kg * 4 + reg, nt * 16 + rl)] = f2bf(a2c[nt][reg] + b2v[nt]);

        #pragma unroll
        for (int p2 = 0; p2 < 2; ++p2) {
            const int hrow = p2 * 8 + (lane >> 3), f0 = (lane & 7) * 8;
            const int sjs = hrow >> 2, sb = hrow & 3;
            const int sj = 4 * pg2 + sjs;
            if (sj < 9) {
                short8 v = *(const short8*)&hlds[hoff + swz(hrow, f0)];
                *(short8*)(upws + ((size_t)(b0 + sb) * 27 + T2 * 9 + sj) * 64 + f0) = v;
            }
        }
    }
}

// ================= Kernel 2: gate GEMM (swapped operands) + epilogue, NO per-tl drains =================
__global__ __launch_bounds__(576, 4)
void k2_gate(const float* __restrict__ z, const unsigned short* __restrict__ upws,
             const short* __restrict__ wsp, const float* __restrict__ gb,
             const float* __restrict__ alphap, float* __restrict__ out)
{
    __shared__ __align__(16) unsigned short ups[27648];  // [b*27 + slot][64] swizzled
    __shared__ __align__(16) unsigned short tscr[9][1024];
    const int t = threadIdx.x;
    const int lane = t & 63;
    const int w = t >> 6;
    const int rl = lane & 15;
    const int kg = lane >> 4;
    const int b0 = blockIdx.x * 16;

    #pragma unroll
    for (int c6 = 0; c6 < 6; ++c6) {
        int chunk = t + c6 * 576;
        int row = chunk >> 3, f0 = (chunk & 7) * 8;
        short8 v = *(const short8*)(upws + (size_t)b0 * 1728 + chunk * 8);
        *(short8*)&ups[swz(row, f0)] = v;
    }
    __syncthreads();

    const short* gwp = wsp + 122880;
    const float alpha = alphap[0];
    float gbl[4][4];
    #pragma unroll
    for (int mt = 0; mt < 4; ++mt)
        #pragma unroll
        for (int reg = 0; reg < 4; ++reg) gbl[mt][reg] = gb[mt * 16 + kg * 4 + reg];

    const int c = w % 3, wg = w / 3;

    #pragma unroll
    for (int tl = 0; tl < 9; ++tl) {
        int e = (wg * 9 + tl) * 16 + rl;
        int b = e / 27, rem = e % 27, R = rem / 3, q = rem % 3, C = c + 3 * q;
        int rowR = b * 27 + R, rowC = b * 27 + 9 + C, rowB = b * 27 + 18 + R;

        f32x4 acc[4];
        #pragma unroll
        for (int mt = 0; mt < 4; ++mt) acc[mt] = (f32x4)0.f;

        #pragma unroll
        for (int s6 = 0; s6 < 6; ++s6) {
            int seg = s6 >> 1;
            int kkp = (s6 < 4) ? s6 : 4 + 2 * c + (s6 - 4);
            int row = (seg == 0) ? rowR : (seg == 1) ? rowC : rowB;
            int f = (s6 & 1) * 32 + kg * 8;
            short8 bfrag = *(const short8*)&ups[swz(row, f)];
            #pragma unroll
            for (int mt = 0; mt < 4; ++mt) {
                short8 afrag = *(const short8*)(gwp + ((kkp * 4 + mt) * 64 + lane) * 8);
                acc[mt] = __builtin_amdgcn_mfma_f32_16x16x32_bf16(afrag, bfrag, acc[mt], 0, 0, 0);
            }
        }

        // tscr[w] is wave-private; same-wave DS ops are in-order -> no drains needed.
        #pragma unroll
        for (int mt = 0; mt < 4; ++mt) {
            short4v du4 = *(const short4v*)&ups[swz(rowR, mt * 16 + kg * 4)];
            short4v dc4 = *(const short4v*)&ups[swz(rowC, mt * 16 + kg * 4)];
            #pragma unroll
            for (int reg = 0; reg < 4; ++reg) {
                int fidx = mt * 16 + kg * 4 + reg;
                float g = sigmoidf(acc[mt][reg] + gbl[mt][reg]);
                float duv = bf2f((unsigned short)du4[reg]);
                float dcv = bf2f((unsigned short)dc4[reg]);
                float dbv = bf2f(ups[swz(rowB, (64 * c + fidx) / 3)]);
                tscr[w][swz(rl, fidx)] = f2bf(alpha * g * (duv + dcv + dbv));
            }
        }
        #pragma unroll
        for (int p = 0; p < 2; ++p) {
            int cl = p * 8 + (lane >> 3), f0 = (lane & 7) * 8;
            int e2 = (wg * 9 + tl) * 16 + cl;
            int b2 = e2 / 27, rem2 = e2 % 27, R2 = rem2 / 3, C2 = c + 3 * (rem2 % 3);
            short8 tv = *(const short8*)&tscr[w][swz(cl, f0)];
            const float* zp = z + (size_t)(b0 + b2) * 5184 + (size_t)(R2 * 9 + C2) * 64 + f0;
            float4 z0 = *(const float4*)zp;
            float4 z1 = *(const float4*)(zp + 4);
            float4 o0, o1;
            o0.x = z0.x + bf2f((unsigned short)tv[0]);
            o0.y = z0.y + bf2f((unsigned short)tv[1]);
            o0.z = z0.z + bf2f((unsigned short)tv[2]);
            o0.w = z0.w + bf2f((unsigned short)tv[3]);
            o1.x = z1.x + bf2f((unsigned short)tv[4]);
            o1.y = z1.y + bf2f((unsigned short)tv[5]);
            o1.z = z1.z + bf2f((unsigned short)tv[6]);
            o1.w = z1.w + bf2f((unsigned short)tv[7]);
            float* op = out + (size_t)(b0 + b2) * 5184 + (size_t)(R2 * 9 + C2) * 64 + f0;
            *(float4*)op = o0;
            *(float4*)(op + 4) = o1;
        }
    }
}

extern "C" void kernel_launch(void* const* d_in, const int* in_sizes, int n_in,
                              void* d_out, int out_size, void* d_ws, size_t ws_size,
                              hipStream_t stream) {
    const float* z   = (const float*)d_in[0];
    const float* w1r = (const float*)d_in[1];
    const float* b1r = (const float*)d_in[2];
    const float* w2r = (const float*)d_in[3];
    const float* b2r = (const float*)d_in[4];
    const float* w1c = (const float*)d_in[5];
    const float* b1c = (const float*)d_in[6];
    const float* w2c = (const float*)d_in[7];
    const float* b2c = (const float*)d_in[8];
    const float* w1b = (const float*)d_in[9];
    const float* b1b = (const float*)d_in[10];
    const float* w2b = (const float*)d_in[11];
    const float* b2b = (const float*)d_in[12];
    const float* gw  = (const float*)d_in[13];
    const float* gb  = (const float*)d_in[14];
    const float* al  = (const float*)d_in[15];
    float* outp = (float*)d_out;
    unsigned short* ws = (unsigned short*)d_ws;

    prepack_kernel<<<70, 256, 0, stream>>>(w1r, w1c, w1b, w2r, w2c, w2b, gw, ws);

    const int Btot = in_sizes[0] / 5184;    // 8192
    unsigned short* upws = ws + UPWS_OFF;
    k1_mlp<<<Btot / 4, 768, 0, stream>>>(z, b1r, b2r, b1c, b2c, b1b, b2b,
                                         (const short*)ws, upws);
    k2_gate<<<Btot / 16, 576, 0, stream>>>(z, upws, (const short*)ws, gb, al, outp);
}

// Round 19
// 161.026 us; speedup vs baseline: 1.1294x; 1.1294x over previous
//
#include <hip/hip_runtime.h>
#include <hip/hip_bf16.h>

typedef __attribute__((ext_vector_type(8))) short short8;
typedef __attribute__((ext_vector_type(4))) short short4v;
typedef __attribute__((ext_vector_type(4))) float f32x4;

__device__ __forceinline__ unsigned short f2bf(float f) {
    union { __hip_bfloat16 b; unsigned short u; } v;
    v.b = __float2bfloat16(f);
    return v.u;
}
__device__ __forceinline__ float bf2f(unsigned short u) {
    return __uint_as_float(((unsigned)u) << 16);
}
__device__ __forceinline__ float gelu_tanh(float x) {
    float u = 0.79788456080286536f * x * (1.0f + 0.044715f * x * x);
    return x * __builtin_amdgcn_rcpf(1.0f + __builtin_exp2f(-2.8853900817779268f * u));
}
__device__ __forceinline__ float sigmoidf(float x) {
    return __builtin_amdgcn_rcpf(1.0f + __builtin_exp2f(-1.4426950408889634f * x));
}
__device__ __forceinline__ int swz(int row, int col) {  // short-index swizzle
    return (row * 64 + col) ^ ((row & 7) << 3);
}

// ---------------- prepack: fp32 weights -> bf16 MFMA fragment layout in ws ----------------
// layout (shorts): W1[m] at m*36864 ; W2[m] at 110592+m*4096 ; GATE(320x64 eff.) at 122880
__global__ __launch_bounds__(256)
void prepack_kernel(const float* __restrict__ w1r, const float* __restrict__ w1c,
                    const float* __restrict__ w1b,
                    const float* __restrict__ w2r, const float* __restrict__ w2c,
                    const float* __restrict__ w2b,
                    const float* __restrict__ gw, unsigned short* __restrict__ ws)
{
    int t = blockIdx.x * 256 + threadIdx.x;
    if (t < 13824) {
        int wi = t / 4608, r = t % 4608;
        const float* src = (wi == 0) ? w1r : (wi == 1) ? w1c : w1b;
        unsigned short* dst = ws + wi * 36864;
        int lane = r & 63;
        int col = ((r >> 6) & 3) * 16 + (lane & 15);
        int k0 = (r >> 8) * 32 + (lane >> 4) * 8;
        #pragma unroll
        for (int j = 0; j < 8; ++j) dst[r * 8 + j] = f2bf(src[(k0 + j) * 64 + col]);
    } else if (t < 15360) {
        int q = t - 13824, wi = q / 512, r = q % 512;
        const float* src = (wi == 0) ? w2r : (wi == 1) ? w2c : w2b;
        unsigned short* dst = ws + 110592 + wi * 4096;
        int lane = r & 63;
        int col = ((r >> 6) & 3) * 16 + (lane & 15);
        int k0 = (r >> 8) * 32 + (lane >> 4) * 8;
        #pragma unroll
        for (int j = 0; j < 8; ++j) dst[r * 8 + j] = f2bf(src[(k0 + j) * 64 + col]);
    } else if (t < 17920) {
        int r = t - 15360;
        unsigned short* dst = ws + 122880;
        int lane = r & 63;
        int col = ((r >> 6) & 3) * 16 + (lane & 15);
        int k0 = (r >> 8) * 32 + (lane >> 4) * 8;
        #pragma unroll
        for (int j = 0; j < 8; ++j) {
            int krow = k0 + j;
            float v;
            if (krow < 128) {
                v = gw[krow * 64 + col];
            } else {
                int c = (krow - 128) >> 6, e = (krow - 128) & 63;
                int lo = 3 * e - 64 * c;
                v = 0.f;
                #pragma unroll
                for (int s = 0; s < 3; ++s) {
                    int dp = lo + s;
                    if (dp >= 0 && dp < 64) v += gw[(128 + dp) * 64 + col];
                }
            }
            dst[r * 8 + j] = f2bf(v);
        }
    }
}

// ================= Kernel 1: NB=4, 12 waves = (type x feature-quarter), weights amortized 3x =================
// ws UP layout (shorts, base UPWS_OFF): [(b*27 + slot)*64 + f], slot: 0-8 row, 9-17 col, 18-26 box
#define UPWS_OFF 147456

__global__ __launch_bounds__(768, 2)
void k1_mlp(const float* __restrict__ z,
            const float* __restrict__ b1r, const float* __restrict__ b2r,
            const float* __restrict__ b1c, const float* __restrict__ b2c,
            const float* __restrict__ b1b, const float* __restrict__ b2b,
            const short* __restrict__ wsp, unsigned short* __restrict__ upws)
{
    __shared__ __align__(16) unsigned short zl[20736];  // 4 b x 81 cells x 64 f (41.5 KB)
    __shared__ __align__(16) unsigned short hlds[9216]; // 9 tiles x 16x64 (18 KB)
    const int t = threadIdx.x;
    const int lane = t & 63;
    const int w = t >> 6;          // 0..11
    const int rl = lane & 15;
    const int kg = lane >> 4;
    const int b0 = blockIdx.x * 4;

    // ---- stage z: 4*5184 floats, coalesced stream, inline f32->bf16 ----
    {
        const float* src = z + (size_t)b0 * 5184;
        for (int g = t; g < 5184; g += 768) {
            float4 v = *(const float4*)(src + g * 4);
            int row = g >> 4;           // b*81 + cell
            int col = (g & 15) * 4;
            uint2 pk;
            pk.x = ((unsigned)f2bf(v.y) << 16) | f2bf(v.x);
            pk.y = ((unsigned)f2bf(v.w) << 16) | f2bf(v.z);
            *(uint2*)&zl[swz(row, col)] = pk;
        }
    }
    __syncthreads();

    // ---- K-loop: wave (T, nq) computes feature quarter nq of all 3 tiles of type T ----
    const int T = w >> 2, nq = w & 3;
    const short* w1p = wsp + T * 36864;
    const float* b1p = (T == 0) ? b1r : (T == 1) ? b1c : b1b;
    const float b1s = b1p[nq * 16 + rl];

    const int b = rl & 3, js = rl >> 2;
    int rb0, rb1, rb2;
    {
        int j0 = 0 * 4 + js;  j0 = (j0 < 9) ? j0 : 8;
        int j1 = 1 * 4 + js;  j1 = (j1 < 9) ? j1 : 8;
        int j2 = 2 * 4 + js;  j2 = (j2 < 9) ? j2 : 8;
        int c0 = (T == 0) ? j0 * 9 : (T == 1) ? j0 : (j0 / 3) * 27 + (j0 % 3) * 3;
        int c1 = (T == 0) ? j1 * 9 : (T == 1) ? j1 : (j1 / 3) * 27 + (j1 % 3) * 3;
        int c2 = (T == 0) ? j2 * 9 : (T == 1) ? j2 : (j2 / 3) * 27 + (j2 % 3) * 3;
        rb0 = b * 81 + c0; rb1 = b * 81 + c1; rb2 = b * 81 + c2;
    }

    f32x4 acc0 = (f32x4)0.f, acc1 = (f32x4)0.f, acc2 = (f32x4)0.f;

    #pragma unroll
    for (int kk = 0; kk < 18; ++kk) {
        const int s = kk >> 1;
        const int sadd = (T == 0) ? s : (T == 1) ? 9 * s : (s / 3) * 9 + (s % 3);
        const int feat = (kk & 1) * 32 + kg * 8;
        short8 bv = *(const short8*)(w1p + ((kk * 4 + nq) * 64 + lane) * 8);
        short8 a0 = *(const short8*)&zl[swz(rb0 + sadd, feat)];
        short8 a1 = *(const short8*)&zl[swz(rb1 + sadd, feat)];
        short8 a2 = *(const short8*)&zl[swz(rb2 + sadd, feat)];
        acc0 = __builtin_amdgcn_mfma_f32_16x16x32_bf16(a0, bv, acc0, 0, 0, 0);
        acc1 = __builtin_amdgcn_mfma_f32_16x16x32_bf16(a1, bv, acc1, 0, 0, 0);
        acc2 = __builtin_amdgcn_mfma_f32_16x16x32_bf16(a2, bv, acc2, 0, 0, 0);
    }

    // ---- gelu+bias -> H (cross-wave assembly: 4 nq-waves fill each tile) ----
    #pragma unroll
    for (int reg = 0; reg < 4; ++reg) {
        hlds[(T * 3 + 0) * 1024 + swz(kg * 4 + reg, nq * 16 + rl)] = f2bf(gelu_tanh(acc0[reg] + b1s));
        hlds[(T * 3 + 1) * 1024 + swz(kg * 4 + reg, nq * 16 + rl)] = f2bf(gelu_tanh(acc1[reg] + b1s));
        hlds[(T * 3 + 2) * 1024 + swz(kg * 4 + reg, nq * 16 + rl)] = f2bf(gelu_tanh(acc2[reg] + b1s));
    }
    __syncthreads();

    // ---- stage 2 + UP store: waves 0..8, tile w (type T2, group pg2) ----
    if (w < 9) {
        const int T2 = w / 3, pg2 = w % 3;
        const int hoff = w * 1024;
        const short* w2p = wsp + 110592 + T2 * 4096;
        const float* b2p = (T2 == 0) ? b2r : (T2 == 1) ? b2c : b2b;
        float b2v[4];
        #pragma unroll
        for (int nt = 0; nt < 4; ++nt) b2v[nt] = b2p[nt * 16 + rl];

        f32x4 a2c[4];
        #pragma unroll
        for (int nt = 0; nt < 4; ++nt) a2c[nt] = (f32x4)0.f;
        #pragma unroll
        for (int kk2 = 0; kk2 < 2; ++kk2) {
            short8 a2 = *(const short8*)&hlds[hoff + swz(rl, kk2 * 32 + kg * 8)];
            #pragma unroll
            for (int nt = 0; nt < 4; ++nt) {
                short8 bw = *(const short8*)(w2p + ((kk2 * 4 + nt) * 64 + lane) * 8);
                a2c[nt] = __builtin_amdgcn_mfma_f32_16x16x32_bf16(a2, bw, a2c[nt], 0, 0, 0);
            }
        }
        asm volatile("s_waitcnt lgkmcnt(0)" ::: "memory");
        #pragma unroll
        for (int nt = 0; nt < 4; ++nt)
            #pragma unroll
            for (int reg = 0; reg < 4; ++reg)
                hlds[hoff + swz(kg * 4 + reg, nt * 16 + rl)] = f2bf(a2c[nt][reg] + b2v[nt]);
        asm volatile("s_waitcnt lgkmcnt(0)" ::: "memory");

        #pragma unroll
        for (int p2 = 0; p2 < 2; ++p2) {
            const int hrow = p2 * 8 + (lane >> 3), f0 = (lane & 7) * 8;
            const int sjs = hrow >> 2, sb = hrow & 3;
            const int sj = 4 * pg2 + sjs;
            if (sj < 9) {
                short8 v = *(const short8*)&hlds[hoff + swz(hrow, f0)];
                *(short8*)(upws + ((size_t)(b0 + sb) * 27 + T2 * 9 + sj) * 64 + f0) = v;
            }
        }
    }
}

// ================= Kernel 2: r17 structure (drains KEPT) + hoisted z loads + static dbcol =================
__global__ __launch_bounds__(576, 4)
void k2_gate(const float* __restrict__ z, const unsigned short* __restrict__ upws,
             const short* __restrict__ wsp, const float* __restrict__ gb,
             const float* __restrict__ alphap, float* __restrict__ out)
{
    __shared__ __align__(16) unsigned short ups[27648];  // [b*27 + slot][64] swizzled
    __shared__ __align__(16) unsigned short tscr[9][1024];
    const int t = threadIdx.x;
    const int lane = t & 63;
    const int w = t >> 6;
    const int rl = lane & 15;
    const int kg = lane >> 4;
    const int b0 = blockIdx.x * 16;

    #pragma unroll
    for (int c6 = 0; c6 < 6; ++c6) {
        int chunk = t + c6 * 576;
        int row = chunk >> 3, f0 = (chunk & 7) * 8;
        short8 v = *(const short8*)(upws + (size_t)b0 * 1728 + chunk * 8);
        *(short8*)&ups[swz(row, f0)] = v;
    }
    __syncthreads();

    const short* gwp = wsp + 122880;
    const float alpha = alphap[0];
    float gbl[4][4];
    #pragma unroll
    for (int mt = 0; mt < 4; ++mt)
        #pragma unroll
        for (int reg = 0; reg < 4; ++reg) gbl[mt][reg] = gb[mt * 16 + kg * 4 + reg];

    const int c = w % 3, wg = w / 3;

    // tl-invariant box-gather columns (lane-static -> registers; kills 16 div-by-3 per tl)
    int dbcol[4][4];
    #pragma unroll
    for (int mt = 0; mt < 4; ++mt)
        #pragma unroll
        for (int reg = 0; reg < 4; ++reg)
            dbcol[mt][reg] = (64 * c + mt * 16 + kg * 4 + reg) / 3;

    #pragma unroll
    for (int tl = 0; tl < 9; ++tl) {
        int e = (wg * 9 + tl) * 16 + rl;
        int b = e / 27, rem = e % 27, R = rem / 3, q = rem % 3, C = c + 3 * q;
        int rowR = b * 27 + R, rowC = b * 27 + 9 + C, rowB = b * 27 + 18 + R;

        // ---- hoisted z loads for the readback (issued before the GEMM, used after) ----
        size_t zoff2[2];
        float4 zpre[2][2];
        #pragma unroll
        for (int p = 0; p < 2; ++p) {
            int cl = p * 8 + (lane >> 3), f0 = (lane & 7) * 8;
            int e2 = (wg * 9 + tl) * 16 + cl;
            int b2 = e2 / 27, rem2 = e2 % 27, R2 = rem2 / 3, C2 = c + 3 * (rem2 % 3);
            zoff2[p] = (size_t)(b0 + b2) * 5184 + (size_t)(R2 * 9 + C2) * 64 + f0;
            zpre[p][0] = *(const float4*)(z + zoff2[p]);
            zpre[p][1] = *(const float4*)(z + zoff2[p] + 4);
        }

        f32x4 acc[4];
        #pragma unroll
        for (int mt = 0; mt < 4; ++mt) acc[mt] = (f32x4)0.f;

        #pragma unroll
        for (int s6 = 0; s6 < 6; ++s6) {
            int seg = s6 >> 1;
            int kkp = (s6 < 4) ? s6 : 4 + 2 * c + (s6 - 4);
            int row = (seg == 0) ? rowR : (seg == 1) ? rowC : rowB;
            int f = (s6 & 1) * 32 + kg * 8;
            short8 bfrag = *(const short8*)&ups[swz(row, f)];
            #pragma unroll
            for (int mt = 0; mt < 4; ++mt) {
                short8 afrag = *(const short8*)(gwp + ((kkp * 4 + mt) * 64 + lane) * 8);
                acc[mt] = __builtin_amdgcn_mfma_f32_16x16x32_bf16(afrag, bfrag, acc[mt], 0, 0, 0);
            }
        }

        // ---- t = alpha*sigmoid(S)*delta -> tscr (drains kept: proven-good schedule) ----
        const int rB64 = rowB * 64, xB = (rowB & 7) << 3;
        #pragma unroll
        for (int mt = 0; mt < 4; ++mt) {
            short4v du4 = *(const short4v*)&ups[swz(rowR, mt * 16 + kg * 4)];
            short4v dc4 = *(const short4v*)&ups[swz(rowC, mt * 16 + kg * 4)];
            #pragma unroll
            for (int reg = 0; reg < 4; ++reg) {
                int fidx = mt * 16 + kg * 4 + reg;
                float g = sigmoidf(acc[mt][reg] + gbl[mt][reg]);
                float duv = bf2f((unsigned short)du4[reg]);
                float dcv = bf2f((unsigned short)dc4[reg]);
                float dbv = bf2f(ups[rB64 + (dbcol[mt][reg] ^ xB)]);
                tscr[w][swz(rl, fidx)] = f2bf(alpha * g * (duv + dcv + dbv));
            }
        }
        asm volatile("s_waitcnt lgkmcnt(0)" ::: "memory");

        // ---- transposed readback -> coalesced fp32 out (z already in registers) ----
        #pragma unroll
        for (int p = 0; p < 2; ++p) {
            int cl = p * 8 + (lane >> 3), f0 = (lane & 7) * 8;
            short8 tv = *(const short8*)&tscr[w][swz(cl, f0)];
            float4 o0, o1;
            o0.x = zpre[p][0].x + bf2f((unsigned short)tv[0]);
            o0.y = zpre[p][0].y + bf2f((unsigned short)tv[1]);
            o0.z = zpre[p][0].z + bf2f((unsigned short)tv[2]);
            o0.w = zpre[p][0].w + bf2f((unsigned short)tv[3]);
            o1.x = zpre[p][1].x + bf2f((unsigned short)tv[4]);
            o1.y = zpre[p][1].y + bf2f((unsigned short)tv[5]);
            o1.z = zpre[p][1].z + bf2f((unsigned short)tv[6]);
            o1.w = zpre[p][1].w + bf2f((unsigned short)tv[7]);
            float* op = out + zoff2[p];
            *(float4*)op = o0;
            *(float4*)(op + 4) = o1;
        }
        asm volatile("s_waitcnt lgkmcnt(0)" ::: "memory");
    }
}

extern "C" void kernel_launch(void* const* d_in, const int* in_sizes, int n_in,
                              void* d_out, int out_size, void* d_ws, size_t ws_size,
                              hipStream_t stream) {
    const float* z   = (const float*)d_in[0];
    const float* w1r = (const float*)d_in[1];
    const float* b1r = (const float*)d_in[2];
    const float* w2r = (const float*)d_in[3];
    const float* b2r = (const float*)d_in[4];
    const float* w1c = (const float*)d_in[5];
    const float* b1c = (const float*)d_in[6];
    const float* w2c = (const float*)d_in[7];
    const float* b2c = (const float*)d_in[8];
    const float* w1b = (const float*)d_in[9];
    const float* b1b = (const float*)d_in[10];
    const float* w2b = (const float*)d_in[11];
    const float* b2b = (const float*)d_in[12];
    const float* gw  = (const float*)d_in[13];
    const float* gb  = (const float*)d_in[14];
    const float* al  = (const float*)d_in[15];
    float* outp = (float*)d_out;
    unsigned short* ws = (unsigned short*)d_ws;

    prepack_kernel<<<70, 256, 0, stream>>>(w1r, w1c, w1b, w2r, w2c, w2b, gw, ws);

    const int Btot = in_sizes[0] / 5184;    // 8192
    unsigned short* upws = ws + UPWS_OFF;
    k1_mlp<<<Btot / 4, 768, 0, stream>>>(z, b1r, b2r, b1c, b2c, b1b, b2b,
                                         (const short*)ws, upws);
    k2_gate<<<Btot / 16, 576, 0, stream>>>(z, upws, (const short*)ws, gb, al, outp);
}